// Round 1
// baseline (4121.707 us; speedup 1.0000x reference)
//
#include <hip/hip_runtime.h>
#include <hip/hip_cooperative_groups.h>
#include <math.h>

namespace cg = cooperative_groups;

#define Bn   32
#define Sn   256
#define En   512
#define Hn   512
#define Wn   512
#define ENCn 1024
#define G4   2048
#define KTOT 1536

// ---------------- workspace offsets (floats) ----------------
// bsum  : [B][S][W]      4194304
// gpart : [8][B][2048]    524288
// qpart : [8][B][512]     131072
// x     : [B][512]         16384
// h     : [2][B][512]      32768
// c     : [2][B][512]      32768
// state : ints (bond[32], nact at 64)

// ---------------- init ----------------
__global__ void init_kernel(const float* __restrict__ hn0, float* __restrict__ x,
                            float* __restrict__ h, float* __restrict__ c,
                            int* __restrict__ state)
{
    int i = blockIdx.x * blockDim.x + threadIdx.x;
    if (i < Bn * Hn) {
        x[i] = 0.0f;
        h[i] = 0.0f;       // h[0] = zeros
        c[i] = hn0[i];     // c[0] = encoder_hn
    }
    if (i < Bn) state[i] = 0;      // bond
    if (i == 0) state[64] = Bn;    // n_active
}

// ---------------- bsum = enc@W1 + emb[wid]@W2 ----------------
// M=8192 (B*S), N=512, K=1536 (1024 enc | 512 emb). 64x64 tile, 4x4/thread.
__global__ __launch_bounds__(256) void bsum_gemm(
    const float* __restrict__ enc, const int* __restrict__ wid,
    const float* __restrict__ emb, const float* __restrict__ W1,
    const float* __restrict__ W2, float* __restrict__ bsum)
{
    __shared__ float As[16][68];   // [k][m]
    __shared__ float Bs[16][68];   // [k][n]
    const int tid  = threadIdx.x;
    const int row0 = blockIdx.y * 64;
    const int col0 = blockIdx.x * 64;
    const int tm0  = (tid & 15) * 4;
    const int tn0  = (tid >> 4) * 4;
    const int la_r = tid >> 2;          // 0..63
    const int la_k = (tid & 3) * 4;     // 0,4,8,12
    const int lb_k = tid >> 4;          // 0..15
    const int lb_n = (tid & 15) * 4;

    float acc[4][4];
#pragma unroll
    for (int i = 0; i < 4; i++)
#pragma unroll
        for (int j = 0; j < 4; j++) acc[i][j] = 0.0f;

    for (int k0 = 0; k0 < KTOT; k0 += 16) {
        // A tile
        const int gr = row0 + la_r;
        float4 av;
        if (k0 < ENCn) {
            av = *(const float4*)&enc[(long)gr * ENCn + k0 + la_k];
        } else {
            const int wv = wid[gr];
            av = *(const float4*)&emb[(long)wv * En + (k0 - ENCn) + la_k];
        }
        As[la_k + 0][la_r] = av.x;
        As[la_k + 1][la_r] = av.y;
        As[la_k + 2][la_r] = av.z;
        As[la_k + 3][la_r] = av.w;
        // B tile
        float4 bv;
        if (k0 < ENCn) bv = *(const float4*)&W1[(long)(k0 + lb_k) * Wn + col0 + lb_n];
        else           bv = *(const float4*)&W2[(long)(k0 - ENCn + lb_k) * Wn + col0 + lb_n];
        *(float4*)&Bs[lb_k][lb_n] = bv;
        __syncthreads();
#pragma unroll
        for (int kk = 0; kk < 16; kk++) {
            float4 a = *(const float4*)&As[kk][tm0];
            float4 b = *(const float4*)&Bs[kk][tn0];
            acc[0][0] += a.x * b.x; acc[0][1] += a.x * b.y; acc[0][2] += a.x * b.z; acc[0][3] += a.x * b.w;
            acc[1][0] += a.y * b.x; acc[1][1] += a.y * b.y; acc[1][2] += a.y * b.z; acc[1][3] += a.y * b.w;
            acc[2][0] += a.z * b.x; acc[2][1] += a.z * b.y; acc[2][2] += a.z * b.z; acc[2][3] += a.z * b.w;
            acc[3][0] += a.w * b.x; acc[3][1] += a.w * b.y; acc[3][2] += a.w * b.z; acc[3][3] += a.w * b.w;
        }
        __syncthreads();
    }
#pragma unroll
    for (int i = 0; i < 4; i++) {
        float4 o = make_float4(acc[i][0], acc[i][1], acc[i][2], acc[i][3]);
        *(float4*)&bsum[(long)(row0 + tm0 + i) * Wn + col0 + tn0] = o;
    }
}

// ---------------- persistent cooperative decode ----------------
__global__ __launch_bounds__(256) void decode_kernel(
    const int* __restrict__ wid, const float* __restrict__ emb,
    const float* __restrict__ Wx, const float* __restrict__ Wh,
    const float* __restrict__ bias, const float* __restrict__ W3,
    const float* __restrict__ W4, const float* __restrict__ vt1,
    const float* __restrict__ bsum,
    float* __restrict__ gpart, float* __restrict__ qpart,
    float* __restrict__ x, float* __restrict__ hbuf, float* __restrict__ cbuf,
    int* __restrict__ state, float* __restrict__ out)
{
    cg::grid_group grid = cg::this_grid();
    __shared__ float sbuf[4608];     // in_t[128][36] for G/Q; q34[0..512)+scores[512..768) for BA
    __shared__ float sv[256];
    __shared__ int   si[256];
    __shared__ int   sbc[2];

    const int wg  = blockIdx.x;    // 256
    const int tid = threadIdx.x;   // 256
    const int lane = tid & 63;
    int* bond = state;
    int* nact = state + 64;

    // hoisted vt1 for BA workgroups
    float vtv[8];
    if (wg < Bn) {
#pragma unroll
        for (int i = 0; i < 8; i++) vtv[i] = vt1[lane + 64 * i];
    }

    for (int step = 0; step < Sn; ++step) {
        const float* hold = hbuf + (step & 1) * (Bn * Hn);
        float*       hnew = hbuf + ((step + 1) & 1) * (Bn * Hn);
        const float* cold = cbuf + (step & 1) * (Bn * Hn);
        float*       cnew = cbuf + ((step + 1) & 1) * (Bn * Hn);

        // ======== PHASE G: gates partials gpart[ks][b][j] ========
        {
            const int ks = wg >> 5, cc = wg & 31;
            const int k0 = ks * 128, j0 = cc * 64;
            const float* src = (k0 < En) ? (x + k0) : (hold + (k0 - En));
            for (int idx = tid; idx < 4096; idx += 256) {
                const int k = idx & 127, b = idx >> 7;
                sbuf[k * 36 + b] = src[b * En + k];
            }
            __syncthreads();
            const float* wmat = (k0 < En) ? (Wx + (long)k0 * G4) : (Wh + (long)(k0 - En) * G4);
            const int col = j0 + lane;
            const int b0  = (tid >> 6) * 8;
            float a0=0,a1=0,a2=0,a3=0,a4=0,a5=0,a6=0,a7=0;
#pragma unroll 4
            for (int k = 0; k < 128; ++k) {
                const float w = wmat[(long)k * G4 + col];
                const float* ip = &sbuf[k * 36 + b0];
                float4 p0 = *(const float4*)ip;
                float4 p1 = *(const float4*)(ip + 4);
                a0 += w * p0.x; a1 += w * p0.y; a2 += w * p0.z; a3 += w * p0.w;
                a4 += w * p1.x; a5 += w * p1.y; a6 += w * p1.z; a7 += w * p1.w;
            }
            float accs[8] = {a0,a1,a2,a3,a4,a5,a6,a7};
#pragma unroll
            for (int i = 0; i < 8; i++)
                gpart[(long)(ks * Bn + b0 + i) * G4 + col] = accs[i];
        }
        grid.sync();

        // ======== PHASE Q: q34 partials + LSTM (redundant, ping-pong h/c) ========
        if (wg < 64) {
            const int ks = wg >> 3, cc = wg & 7;
            const int k0 = ks * 128, j0 = cc * 64;
            if (k0 < En) {
                // gather emb[wid[b, bidx]] slice
                for (int idx = tid; idx < 4096; idx += 256) {
                    const int k = idx & 127, b = idx >> 7;
                    const int bd = bond[b];
                    const int bidx = bd < Sn ? bd : (Sn - 1);
                    sbuf[k * 36 + b] = emb[(long)wid[b * Sn + bidx] * En + k0 + k];
                }
            } else {
                // LSTM for h index j = k0-512+k
                for (int idx = tid; idx < 4096; idx += 256) {
                    const int k = idx & 127, b = idx >> 7;
                    const int j = (k0 - En) + k;
                    float ig = bias[j], fg = bias[512 + j], gg = bias[1024 + j], og = bias[1536 + j];
#pragma unroll
                    for (int p = 0; p < 8; ++p) {
                        const float* gp = gpart + (long)(p * Bn + b) * G4;
                        ig += gp[j]; fg += gp[512 + j]; gg += gp[1024 + j]; og += gp[1536 + j];
                    }
                    const float co  = cold[b * Hn + j];
                    const float sf  = 1.0f / (1.0f + expf(-fg));
                    const float sig = 1.0f / (1.0f + expf(-ig));
                    const float so  = 1.0f / (1.0f + expf(-og));
                    const float cn  = sf * co + sig * tanhf(gg);
                    const float hn_ = so * tanhf(cn);
                    const bool done = bond[b] >= Sn;
                    const float h2 = done ? hold[b * Hn + j] : hn_;
                    const float c2 = done ? co : cn;
                    sbuf[k * 36 + b] = h2;
                    if (cc == 0) { hnew[b * Hn + j] = h2; cnew[b * Hn + j] = c2; }
                }
            }
            __syncthreads();
            const float* wmat = (k0 < En) ? (W3 + (long)k0 * Wn) : (W4 + (long)(k0 - En) * Wn);
            const int col = j0 + lane;
            const int b0  = (tid >> 6) * 8;
            float a0=0,a1=0,a2=0,a3=0,a4=0,a5=0,a6=0,a7=0;
#pragma unroll 4
            for (int k = 0; k < 128; ++k) {
                const float w = wmat[(long)k * Wn + col];
                const float* ip = &sbuf[k * 36 + b0];
                float4 p0 = *(const float4*)ip;
                float4 p1 = *(const float4*)(ip + 4);
                a0 += w * p0.x; a1 += w * p0.y; a2 += w * p0.z; a3 += w * p0.w;
                a4 += w * p1.x; a5 += w * p1.y; a6 += w * p1.z; a7 += w * p1.w;
            }
            float accs[8] = {a0,a1,a2,a3,a4,a5,a6,a7};
#pragma unroll
            for (int i = 0; i < 8; i++)
                qpart[(long)(ks * Bn + b0 + i) * Wn + col] = accs[i];
        }
        grid.sync();

        // ======== PHASE BA: blend+score+argmax+state+next-x (1 WG per batch) ========
        if (wg < Bn) {
            const int b  = wg;
            const int bd = bond[b];
            if (bd < Sn) {
                // q34[b][:] = sum of 8 partials
                for (int j = tid; j < Wn; j += 256) {
                    float s = 0.0f;
#pragma unroll
                    for (int p = 0; p < 8; ++p) s += qpart[(long)(p * Bn + b) * Wn + j];
                    sbuf[j] = s;
                }
                __syncthreads();
                float qv[8];
#pragma unroll
                for (int i = 0; i < 8; i++) qv[i] = sbuf[lane + 64 * i];
                const int wv = tid >> 6;
                const float* brow_base = bsum + (long)b * Sn * Wn;
                for (int p = bd + wv; p < Sn; p += 4) {
                    const float* row = brow_base + (long)p * Wn + lane;
                    float a = 0.0f;
#pragma unroll
                    for (int i = 0; i < 8; i++)
                        a += tanhf(row[64 * i] + qv[i]) * vtv[i];
#pragma unroll
                    for (int off = 32; off; off >>= 1) a += __shfl_xor(a, off, 64);
                    if (lane == 0) sbuf[512 + p] = a;
                }
                __syncthreads();
                // argmax over [bd, 256), first-index tie-break
                float v = -3.402823e38f; int vi = Sn;
                if (tid >= bd) { v = sbuf[512 + tid]; vi = tid; }
                sv[tid] = v; si[tid] = vi;
                __syncthreads();
                for (int off = 128; off; off >>= 1) {
                    if (tid < off) {
                        const float v2 = sv[tid + off]; const int i2 = si[tid + off];
                        if (v2 > sv[tid] || (v2 == sv[tid] && i2 < si[tid])) { sv[tid] = v2; si[tid] = i2; }
                    }
                    __syncthreads();
                }
                if (tid == 0) {
                    const int idxm = si[0];
                    const int nb2 = (idxm > bd) ? idxm : (bd + 1);
                    if (nb2 < Sn) out[nb2 * Bn + b] = 1.0f;
                    bond[b] = nb2;
                    if (nb2 >= Sn) atomicSub(nact, 1);
                    sbc[0] = nb2;
                }
                __syncthreads();
                const int nb2 = sbc[0];
                if (nb2 < Sn) {
                    const int len = nb2 - bd;   // >= 1
                    for (int e = tid; e < En; e += 256) {
                        float s = 0.0f;
                        for (int s2 = bd; s2 < nb2; ++s2)
                            s += emb[(long)wid[b * Sn + s2] * En + e];
                        x[b * En + e] = s / (float)len;
                    }
                }
            }
        }
        grid.sync();
        if (*(volatile int*)nact == 0) break;
    }
}

extern "C" void kernel_launch(void* const* d_in, const int* in_sizes, int n_in,
                              void* d_out, int out_size, void* d_ws, size_t ws_size,
                              hipStream_t stream)
{
    const int*   wid  = (const int*)d_in[0];
    const float* enc  = (const float*)d_in[1];
    const float* hn0  = (const float*)d_in[2];
    const float* emb  = (const float*)d_in[3];
    // d_in[4] chunk_emb : unused (uniform shift, argmax-invariant)
    const float* W1   = (const float*)d_in[5];
    const float* W2   = (const float*)d_in[6];
    const float* W3   = (const float*)d_in[7];
    const float* W4   = (const float*)d_in[8];
    const float* vt1  = (const float*)d_in[9];
    // d_in[10] vt2 : unused
    const float* Wx   = (const float*)d_in[11];
    const float* Wh   = (const float*)d_in[12];
    const float* bias = (const float*)d_in[13];

    float* ws    = (float*)d_ws;
    float* bsum  = ws;
    float* gpart = ws + 4194304;
    float* qpart = gpart + 524288;
    float* x     = qpart + 131072;
    float* h     = x + 16384;
    float* c     = h + 32768;
    int*   state = (int*)(c + 32768);
    float* out   = (float*)d_out;

    hipMemsetAsync(d_out, 0, (size_t)Sn * Bn * sizeof(float), stream);
    hipLaunchKernelGGL(init_kernel, dim3(64), dim3(256), 0, stream, hn0, x, h, c, state);
    hipLaunchKernelGGL(bsum_gemm, dim3(8, 128), dim3(256), 0, stream, enc, wid, emb, W1, W2, bsum);

    void* args[] = { (void*)&wid, (void*)&emb, (void*)&Wx, (void*)&Wh, (void*)&bias,
                     (void*)&W3, (void*)&W4, (void*)&vt1, (void*)&bsum,
                     (void*)&gpart, (void*)&qpart, (void*)&x, (void*)&h, (void*)&c,
                     (void*)&state, (void*)&out };
    hipLaunchCooperativeKernel((void*)decode_kernel, dim3(256), dim3(256), args, 0, stream);
}